// Round 6
// baseline (335.270 us; speedup 1.0000x reference)
//
#include <hip/hip_runtime.h>

#define NSLOPE 0.2f
#define CAP 128            // bucket capacity per dst node (max degree ~66 incl. self-loop)

typedef __bf16 bf16x8 __attribute__((ext_vector_type(8)));
typedef __bf16 bf16x4 __attribute__((ext_vector_type(4)));
typedef __bf16 bf16x2 __attribute__((ext_vector_type(2)));
typedef float  f32x4  __attribute__((ext_vector_type(4)));
typedef _Float16 half2v __attribute__((ext_vector_type(2)));

// fp16 pair dot with f32 accumulate: one v_dot2_f32_f16 when available.
static __device__ __forceinline__ float dot2f(unsigned p, unsigned a, float c){
#if __has_builtin(__builtin_amdgcn_fdot2)
  return __builtin_amdgcn_fdot2(__builtin_bit_cast(half2v, p),
                                __builtin_bit_cast(half2v, a), c, false);
#else
  half2v ph = __builtin_bit_cast(half2v, p), ah = __builtin_bit_cast(half2v, a);
  return c + (float)ph[0]*(float)ah[0] + (float)ph[1]*(float)ah[1];
#endif
}

// ============================================================================
// FRAME LAYOUT: matrix [R rows][K2 cols] bf16 stored as frames of 16 rows x
// 32 k. Frame (rb, kf) holds lane slot = (row&15) + 16*((k>>3)&3), elem k&7.
// Element addr (bf16 units) = rb*(K2*16) + kf*512 + slot*8 + (k&7).
// A GEMM fragment load is then ptr + f*512 + lane*8 : contiguous 1KB/instr.
// ============================================================================

// ===== bucket fill: append edges after prep pre-inserted self-loops =========
__global__ void fill_kernel(const int* __restrict__ ei, int E,
                            int* cnt, int* __restrict__ col){
  int i = blockIdx.x*blockDim.x + threadIdx.x;
  if (i < E){
    int s = ei[i], d = ei[E + i];
    int slot = atomicAdd(&cnt[d], 1);
    if (slot < CAP) col[(d << 7) + slot] = s;   // CAP==128
  }
}

// ===== W [K][Nc] fp32 -> frame-layout split B (hi @ k, lo @ K+k), K2=2K ====
__device__ __forceinline__ void wsplit_body(
    const float* __restrict__ W, __bf16* __restrict__ Bt, int K, int Nc,
    int kb, int nb, float (*hi_s)[33], float (*lo_s)[33]){
  int tx = threadIdx.x & 31, ty = threadIdx.x >> 5;   // 32 x 8
  int k0 = kb * 32, n0 = nb * 32;
#pragma unroll
  for (int i = 0; i < 4; i++){
    int r = ty + i*8;
    float v = W[(size_t)(k0 + r)*Nc + n0 + tx];
    float h = (float)(__bf16)v;
    hi_s[r][tx] = h;
    lo_s[r][tx] = v - h;
  }
  __syncthreads();
  const size_t K2x16 = (size_t)(2*K) * 16;     // 16-row block stride
  const size_t lo_off = (size_t)(K >> 5) * 512;
#pragma unroll
  for (int i = 0; i < 4; i++){
    int n = ty + i*8;
    int r = n0 + n;                            // B row = W col
    size_t a = (size_t)(r >> 4)*K2x16 + (size_t)(k0 >> 5)*512
             + (size_t)((r & 15) + 16*(tx >> 3))*8 + (tx & 7);
    Bt[a]          = (__bf16)hi_s[tx][n];
    Bt[a + lo_off] = (__bf16)lo_s[tx][n];
  }
}

// ===== fused prep: cnt=1 + self-loop col + al zero + split(x) + wsplit(W*) ==
__global__ __launch_bounds__(256) void prep_kernel(
    const float* __restrict__ x, __bf16* __restrict__ X2,
    const float* __restrict__ W1, __bf16* __restrict__ B1t,
    const float* __restrict__ W2, __bf16* __restrict__ B2t,
    const float* __restrict__ W3, __bf16* __restrict__ B3t,
    int* __restrict__ cnt, int* __restrict__ col,
    float* __restrict__ albase, int N){
  __shared__ float hi_s[32][33], lo_s[32][33];
  int b = blockIdx.x, t = threadIdx.x;
  int gid = b*256 + t;
  if (gid < N){
    cnt[gid] = 1;                  // self-loop pre-count
    col[gid << 7] = gid;           // self-loop entry at slot 0
  }
  // zero al_s/al_d for all 3 layers: 18N floats contiguous, float4 stores
  if (gid*4 < N*18) *(float4*)(albase + gid*4) = make_float4(0.f,0.f,0.f,0.f);

  const int nb_split = (N*32 + 255) / 256;   // 1250
  if (b < nb_split){
    int i = gid * 4;
    if (i < N*128){
      int n = i >> 7, c = i & 127;           // 4 consecutive channels, 8-aligned block
      float4 v = *(const float4*)(x + i);
      float f[4] = {v.x, v.y, v.z, v.w};
      bf16x4 h, l;
#pragma unroll
      for (int u = 0; u < 4; u++){
        __bf16 hh = (__bf16)f[u];
        h[u] = hh;
        l[u] = (__bf16)(f[u] - (float)hh);
      }
      // frame layout, K2=256: hi at k=c, lo at k=128+c (kf += 4)
      size_t a = (size_t)(n >> 4)*4096 + (size_t)(c >> 5)*512
               + (size_t)((n & 15) + 16*((c >> 3) & 3))*8 + (c & 7);
      *(bf16x4*)(X2 + a)        = h;
      *(bf16x4*)(X2 + a + 2048) = l;
    }
  } else if (b < nb_split + 64){
    int bb = b - nb_split;                   // W1: K=128 -> 4 x 16
    wsplit_body(W1, B1t, 128, 512, bb & 3, bb >> 2, hi_s, lo_s);
  } else if (b < nb_split + 64 + 256){
    int bb = b - nb_split - 64;              // W2: 16 x 16
    wsplit_body(W2, B2t, 512, 512, bb & 15, bb >> 4, hi_s, lo_s);
  } else {
    int bb = b - nb_split - 320;             // W3: 16 x 16
    wsplit_body(W3, B3t, 512, 512, bb & 15, bb >> 4, hi_s, lo_s);
  }
}

// ========== bf16 MFMA GEMM over K2=2K (hi|lo fold), f16 output ==============
// NO LDS, NO barriers (R5-verified). Operands in frame layout -> contiguous
// 1KB coalesced loads direct to VGPRs. Hb now fp16 (10-bit mantissa) for the
// dot2-based aggregation.
template<int H>
__global__ __launch_bounds__(256) void gemm_mfma(
    const __bf16* __restrict__ A2f, const __bf16* __restrict__ B2f,
    _Float16* __restrict__ Hb, const float* __restrict__ asrc,
    const float* __restrict__ adst, float* __restrict__ al_s,
    float* __restrict__ al_d, int M, int K2){
  int t = threadIdx.x, w = t >> 6, lane = t & 63;
  int mm = lane & 15, q = lane >> 4;

  int bid = blockIdx.x;
  int idx = bid >> 3;
  int cb = idx & 3;
  int rowblk = (bid & 7) + ((idx >> 2) << 3);   // xcd-pinned row panels
  if (rowblk * 64 >= M) return;
  int bm = rowblk * 64, bn = cb * 128;
  int wr = w & 1, wc = w >> 1;

  const int nf = K2 >> 5;                 // frames per row-block
  const int rbmax = (M >> 4) - 1;
  const __bf16* pA0; const __bf16* pA1;
  const __bf16* pB0; const __bf16* pB1; const __bf16* pB2; const __bf16* pB3;
  {
    int rb0 = (bm >> 4) + wr*2;     rb0 = (rb0 <= rbmax) ? rb0 : rbmax;
    int rb1 = (bm >> 4) + wr*2 + 1; rb1 = (rb1 <= rbmax) ? rb1 : rbmax;
    pA0 = A2f + (size_t)rb0*nf*512 + lane*8;
    pA1 = A2f + (size_t)rb1*nf*512 + lane*8;
    int rbB = (bn >> 4) + wc*4;
    pB0 = B2f + (size_t)(rbB+0)*nf*512 + lane*8;
    pB1 = B2f + (size_t)(rbB+1)*nf*512 + lane*8;
    pB2 = B2f + (size_t)(rbB+2)*nf*512 + lane*8;
    pB3 = B2f + (size_t)(rbB+3)*nf*512 + lane*8;
  }

  f32x4 acc[2][4];
#pragma unroll
  for (int i = 0; i < 2; i++)
#pragma unroll
    for (int j = 0; j < 4; j++)
#pragma unroll
      for (int r = 0; r < 4; r++) acc[i][j][r] = 0.f;

#pragma unroll 4
  for (int f = 0; f < nf; f++){
    bf16x8 a0 = *(const bf16x8*)(pA0 + (size_t)f*512);
    bf16x8 a1 = *(const bf16x8*)(pA1 + (size_t)f*512);
    bf16x8 b0 = *(const bf16x8*)(pB0 + (size_t)f*512);
    bf16x8 b1 = *(const bf16x8*)(pB1 + (size_t)f*512);
    bf16x8 b2 = *(const bf16x8*)(pB2 + (size_t)f*512);
    bf16x8 b3 = *(const bf16x8*)(pB3 + (size_t)f*512);
    acc[0][0] = __builtin_amdgcn_mfma_f32_16x16x32_bf16(a0, b0, acc[0][0], 0, 0, 0);
    acc[0][1] = __builtin_amdgcn_mfma_f32_16x16x32_bf16(a0, b1, acc[0][1], 0, 0, 0);
    acc[0][2] = __builtin_amdgcn_mfma_f32_16x16x32_bf16(a0, b2, acc[0][2], 0, 0, 0);
    acc[0][3] = __builtin_amdgcn_mfma_f32_16x16x32_bf16(a0, b3, acc[0][3], 0, 0, 0);
    acc[1][0] = __builtin_amdgcn_mfma_f32_16x16x32_bf16(a1, b0, acc[1][0], 0, 0, 0);
    acc[1][1] = __builtin_amdgcn_mfma_f32_16x16x32_bf16(a1, b1, acc[1][1], 0, 0, 0);
    acc[1][2] = __builtin_amdgcn_mfma_f32_16x16x32_bf16(a1, b2, acc[1][2], 0, 0, 0);
    acc[1][3] = __builtin_amdgcn_mfma_f32_16x16x32_bf16(a1, b3, acc[1][3], 0, 0, 0);
  }

  // ---- epilogue: Hb store (f16) + fused attention dots -----------------
  float as_v[4], ad_v[4];
#pragma unroll
  for (int j2 = 0; j2 < 4; j2++){
    int colc = bn + (wc*4 + j2)*16 + mm;
    as_v[j2] = asrc[colc];
    ad_v[j2] = adst[colc];
  }
  const int h = (H == 4) ? (bn >> 7) : 0;
#pragma unroll
  for (int i2 = 0; i2 < 2; i2++){
    int rbase = bm + (wr*2 + i2)*16 + q*4;
#pragma unroll
    for (int j2 = 0; j2 < 4; j2++){
      int colc = bn + (wc*4 + j2)*16 + mm;
#pragma unroll
      for (int r = 0; r < 4; r++){
        int row = rbase + r;
        if (row < M) Hb[(size_t)row*512 + colc] = (_Float16)acc[i2][j2][r];
      }
    }
#pragma unroll
    for (int r = 0; r < 4; r++){
      float ps = acc[i2][0][r]*as_v[0] + acc[i2][1][r]*as_v[1]
               + acc[i2][2][r]*as_v[2] + acc[i2][3][r]*as_v[3];
      float pd = acc[i2][0][r]*ad_v[0] + acc[i2][1][r]*ad_v[1]
               + acc[i2][2][r]*ad_v[2] + acc[i2][3][r]*ad_v[3];
#pragma unroll
      for (int off = 1; off < 16; off <<= 1){
        ps += __shfl_xor(ps, off);
        pd += __shfl_xor(pd, off);
      }
      int row = rbase + r;
      if (mm == 0 && row < M){
        atomicAdd(&al_s[(size_t)row*H + h], ps);
        atomicAdd(&al_d[(size_t)row*H + h], pd);
      }
    }
  }
}

// ====== per-node gather: 256 thr = 4 independent waves (1 per head-slice) ===
// Wave w handles channels [w*128, w*128+128), 2 ch/lane (one u32 of f16x2).
// No barriers: LDS is wave-private, lanes are lockstep. Softmax logits are
// gathered ONCE into registers (<=2 chunks of 64). Inner loop processes edge
// PAIRS: 2 u32 row loads + 2 bitop packs + 2 v_dot2_f32_f16 per 2 edges.
template<int H, int MODE>
__global__ __launch_bounds__(256) void aggregate_slice(
    const _Float16* __restrict__ Hb, const float* __restrict__ al_s,
    const float* __restrict__ al_d, const int* __restrict__ cnt,
    const int* __restrict__ col, const float* __restrict__ bias,
    float* __restrict__ outF, __bf16* __restrict__ fA, int N){
  __shared__ int      src_s[4][64];
  __shared__ _Float16 a_sh[4][64];
  int d = blockIdx.x;
  if (d >= N) return;
  int t = threadIdx.x, w = t >> 6, lane = t & 63;
  const int hh = (H == 1) ? 0 : w;
  const float ald = al_d[(size_t)d*H + hh];
  int deg = cnt[d]; deg = (deg < CAP) ? deg : CAP;
  int start = d << 7;

  // gather logits once (<= 2 chunks), keep in registers
  int sc0 = 0, sc1 = 0;
  float v0f = -1e30f, v1f = -1e30f;
  if (lane < deg){
    sc0 = col[start + lane];
    float v = al_s[(size_t)sc0*H + hh] + ald;
    v0f = (v > 0.f) ? v : NSLOPE * v;
  }
  if (64 + lane < deg){
    sc1 = col[start + 64 + lane];
    float v = al_s[(size_t)sc1*H + hh] + ald;
    v1f = (v > 0.f) ? v : NSLOPE * v;
  }
  float mx = fmaxf(v0f, v1f);
#pragma unroll
  for (int off = 32; off > 0; off >>= 1)
    mx = fmaxf(mx, __shfl_xor(mx, off));

  float e0 = (lane < deg)      ? __expf(v0f - mx) : 0.f;
  float e1 = (64 + lane < deg) ? __expf(v1f - mx) : 0.f;
  float lsum = e0 + e1;
#pragma unroll
  for (int off = 32; off > 0; off >>= 1)
    lsum += __shfl_xor(lsum, off);

  const unsigned* __restrict__ Hb32 = (const unsigned*)Hb;   // row = 256 u32
  const unsigned coffu = w*64 + lane;                        // channel pair idx
  float accx = 0.f, accy = 0.f;

  int cc0 = (deg < 64) ? deg : 64;       // chunk A count
  src_s[w][lane] = sc0;
  a_sh[w][lane]  = (_Float16)e0;
  for (int chunk = 0; ; chunk++){
    int cnt2 = (chunk == 0) ? cc0 : (deg - 64);
    int npair = cnt2 >> 1;
    int j = 0;
    for (; j + 2 <= npair; j += 2){
      int s0 = src_s[w][2*j],     s1 = src_s[w][2*j+1];
      int s2 = src_s[w][2*j+2],   s3 = src_s[w][2*j+3];
      unsigned a01 = *(const unsigned*)&a_sh[w][2*j];
      unsigned a23 = *(const unsigned*)&a_sh[w][2*j+2];
      unsigned u0 = Hb32[(size_t)s0*256 + coffu];
      unsigned u1 = Hb32[(size_t)s1*256 + coffu];
      unsigned u2 = Hb32[(size_t)s2*256 + coffu];
      unsigned u3 = Hb32[(size_t)s3*256 + coffu];
      unsigned pc  = (u0 & 0x0000ffffu) | (u1 << 16);   // (e0_c , e1_c )
      unsigned pc1 = (u0 >> 16) | (u1 & 0xffff0000u);   // (e0_c1, e1_c1)
      unsigned qc  = (u2 & 0x0000ffffu) | (u3 << 16);
      unsigned qc1 = (u2 >> 16) | (u3 & 0xffff0000u);
      accx = dot2f(pc,  a01, accx);
      accy = dot2f(pc1, a01, accy);
      accx = dot2f(qc,  a23, accx);
      accy = dot2f(qc1, a23, accy);
    }
    for (; j < npair; j++){
      int s0 = src_s[w][2*j], s1 = src_s[w][2*j+1];
      unsigned a01 = *(const unsigned*)&a_sh[w][2*j];
      unsigned u0 = Hb32[(size_t)s0*256 + coffu];
      unsigned u1 = Hb32[(size_t)s1*256 + coffu];
      unsigned pc  = (u0 & 0x0000ffffu) | (u1 << 16);
      unsigned pc1 = (u0 >> 16) | (u1 & 0xffff0000u);
      accx = dot2f(pc,  a01, accx);
      accy = dot2f(pc1, a01, accy);
    }
    if (cnt2 & 1){
      int sl = src_s[w][cnt2 - 1];
      float al = (float)a_sh[w][cnt2 - 1];
      unsigned ul = Hb32[(size_t)sl*256 + coffu];
      half2v hv = __builtin_bit_cast(half2v, ul);
      accx += al * (float)hv[0];
      accy += al * (float)hv[1];
    }
    if (chunk == 1 || deg <= 64) break;
    // lockstep wave: all lanes finished chunk-A reads before this write
    src_s[w][lane] = sc1;
    a_sh[w][lane]  = (_Float16)e1;
  }

  float invd = 1.f / lsum;
  int c = w*128 + lane*2;
  float2 bv = *(const float2*)(bias + c);
  float r0 = accx * invd + bv.x;
  float r1 = accy * invd + bv.y;
  if (MODE == 1){
    r0 = fmaxf(r0, 0.f); r1 = fmaxf(r1, 0.f);
    __bf16 h0 = (__bf16)r0, h1 = (__bf16)r1;
    bf16x2 hv; hv[0] = h0; hv[1] = h1;
    bf16x2 lv; lv[0] = (__bf16)(r0 - (float)h0); lv[1] = (__bf16)(r1 - (float)h1);
    // frame layout write (K2=1024): hi at k=c, lo at k=512+c
    size_t a = (size_t)(d >> 4)*16384 + (size_t)(c >> 5)*512
             + (size_t)((d & 15) + 16*((c >> 3) & 3))*8 + (c & 7);
    *(bf16x2*)(fA + a)        = hv;
    *(bf16x2*)(fA + a + 8192) = lv;
  } else {
    *(float2*)(outF + (size_t)d*512 + c) = make_float2(r0, r1);
  }
}

// =========================== launch =========================================
extern "C" void kernel_launch(void* const* d_in, const int* in_sizes, int n_in,
                              void* d_out, int out_size, void* d_ws, size_t ws_size,
                              hipStream_t stream){
  const float* x   = (const float*)d_in[0];
  const int*   ei  = (const int*)  d_in[1];
  const float* W1  = (const float*)d_in[2];
  const float* as1 = (const float*)d_in[3];
  const float* ad1 = (const float*)d_in[4];
  const float* b1  = (const float*)d_in[5];
  const float* W2  = (const float*)d_in[6];
  const float* as2 = (const float*)d_in[7];
  const float* ad2 = (const float*)d_in[8];
  const float* b2  = (const float*)d_in[9];
  const float* W3  = (const float*)d_in[10];
  const float* as3 = (const float*)d_in[11];
  const float* ad3 = (const float*)d_in[12];
  const float* b3  = (const float*)d_in[13];
  float* out = (float*)d_out;

  const int N = in_sizes[0] / 128;   // 10000
  const int E = in_sizes[1] / 2;     // 320000

  // workspace carve-up
  __bf16* feat2  = (__bf16*)d_ws;                     // N*1024 bf16 (frame, hi|lo)
  __bf16* X2     = feat2 + (size_t)N*1024;            // N*256 bf16 (frame, layer-1 A)
  float*  albase = (float*)(X2 + (size_t)N*256);      // 18*N floats total:
  float*  als1   = albase;                            //  N*4
  float*  ald1   = als1 + (size_t)N*4;                //  N*4
  float*  als2   = ald1 + (size_t)N*4;                //  N*4
  float*  ald2   = als2 + (size_t)N*4;                //  N*4
  float*  als3   = ald2 + (size_t)N*4;                //  N
  float*  ald3   = als3 + (size_t)N;                  //  N
  int*    cnt    = (int*)(ald3 + (size_t)N);          // N
  int*    col    = cnt + N;                           // N*CAP
  uintptr_t p  = (uintptr_t)(col + (size_t)N*CAP);
  p = (p + 15) & ~(uintptr_t)15;
  __bf16* B1t = (__bf16*)p;                           // 512*256 bf16 (frame)
  __bf16* B2t = B1t + 512*256;                        // 512*1024 bf16 (frame)
  __bf16* B3t = B2t + 512*1024;                       // 512*1024 bf16 (frame)
  _Float16* Hb = (_Float16*)(B3t + 512*1024);         // N*512 f16 (row-major, gather)

  const int nb_split = (N*32 + 255)/256;              // 1250
  const int pgrid = nb_split + 64 + 256 + 256;        // 1826

  // prep: cnt=1 + self-loop col + al-zero, split x, split W1/W2/W3
  prep_kernel<<<pgrid, 256, 0, stream>>>(x, X2, W1, B1t, W2, B2t, W3, B3t,
                                         cnt, col, albase, N);
  fill_kernel<<<(E+255)/256, 256, 0, stream>>>(ei, E, cnt, col);

  const int nrb = (N + 63)/64;                        // 157 row panels (BM=64)
  const int ggrid = (((nrb + 7) >> 3) << 3) * 4;      // 160*4 = 640 (XCD map)

  // ---- layer 1: x[N,128] @ W1[128,512]  (K2 = 256) ----
  gemm_mfma<4><<<ggrid, 256, 0, stream>>>(X2, B1t, Hb, as1, ad1, als1, ald1, N, 256);
  aggregate_slice<4,1><<<N, 256, 0, stream>>>(Hb, als1, ald1, cnt, col, b1,
      (float*)nullptr, feat2, N);

  // ---- layer 2: feat[N,512] @ W2[512,512]  (K2 = 1024) ----
  gemm_mfma<4><<<ggrid, 256, 0, stream>>>(feat2, B2t, Hb, as2, ad2, als2, ald2, N, 1024);
  aggregate_slice<4,1><<<N, 256, 0, stream>>>(Hb, als2, ald2, cnt, col, b2,
      (float*)nullptr, feat2, N);

  // ---- layer 3: feat[N,512] @ W3[512,512], heads=1  (K2 = 1024) ----
  gemm_mfma<1><<<ggrid, 256, 0, stream>>>(feat2, B3t, Hb, as3, ad3, als3, ald3, N, 1024);
  aggregate_slice<1,0><<<N, 256, 0, stream>>>(Hb, als3, ald3, cnt, col, b3,
      out, (__bf16*)nullptr, N);
}

// Round 7
// 288.449 us; speedup vs baseline: 1.1623x; 1.1623x over previous
//
#include <hip/hip_runtime.h>

#define NSLOPE 0.2f
#define CAP 128            // bucket capacity per dst node (max degree ~66 incl. self-loop)

typedef __bf16 bf16x8 __attribute__((ext_vector_type(8)));
typedef __bf16 bf16x4 __attribute__((ext_vector_type(4)));
typedef __bf16 bf16x2 __attribute__((ext_vector_type(2)));
typedef float  f32x4  __attribute__((ext_vector_type(4)));
typedef _Float16 half2v __attribute__((ext_vector_type(2)));

// fp16 pair dot with f32 accumulate: one v_dot2_f32_f16 when available.
static __device__ __forceinline__ float dot2f(unsigned p, unsigned a, float c){
#if __has_builtin(__builtin_amdgcn_fdot2)
  return __builtin_amdgcn_fdot2(__builtin_bit_cast(half2v, p),
                                __builtin_bit_cast(half2v, a), c, false);
#else
  half2v ph = __builtin_bit_cast(half2v, p), ah = __builtin_bit_cast(half2v, a);
  return c + (float)ph[0]*(float)ah[0] + (float)ph[1]*(float)ah[1];
#endif
}

// ============================================================================
// FRAME LAYOUT: matrix [R rows][K2 cols] bf16 stored as frames of 16 rows x
// 32 k. Frame (rb, kf) holds lane slot = (row&15) + 16*((k>>3)&3), elem k&7.
// Element addr (bf16 units) = rb*(K2*16) + kf*512 + slot*8 + (k&7).
// A GEMM fragment load is then ptr + f*512 + lane*8 : contiguous 1KB/instr.
// ============================================================================

// ===== bucket fill: append edges after prep pre-inserted self-loops =========
__global__ void fill_kernel(const int* __restrict__ ei, int E,
                            int* cnt, int* __restrict__ col){
  int i = blockIdx.x*blockDim.x + threadIdx.x;
  if (i < E){
    int s = ei[i], d = ei[E + i];
    int slot = atomicAdd(&cnt[d], 1);
    if (slot < CAP) col[(d << 7) + slot] = s;   // CAP==128
  }
}

// ===== W [K][Nc] fp32 -> frame-layout split B (hi @ k, lo @ K+k), K2=2K ====
__device__ __forceinline__ void wsplit_body(
    const float* __restrict__ W, __bf16* __restrict__ Bt, int K, int Nc,
    int kb, int nb, float (*hi_s)[33], float (*lo_s)[33]){
  int tx = threadIdx.x & 31, ty = threadIdx.x >> 5;   // 32 x 8
  int k0 = kb * 32, n0 = nb * 32;
#pragma unroll
  for (int i = 0; i < 4; i++){
    int r = ty + i*8;
    float v = W[(size_t)(k0 + r)*Nc + n0 + tx];
    float h = (float)(__bf16)v;
    hi_s[r][tx] = h;
    lo_s[r][tx] = v - h;
  }
  __syncthreads();
  const size_t K2x16 = (size_t)(2*K) * 16;     // 16-row block stride
  const size_t lo_off = (size_t)(K >> 5) * 512;
#pragma unroll
  for (int i = 0; i < 4; i++){
    int n = ty + i*8;
    int r = n0 + n;                            // B row = W col
    size_t a = (size_t)(r >> 4)*K2x16 + (size_t)(k0 >> 5)*512
             + (size_t)((r & 15) + 16*(tx >> 3))*8 + (tx & 7);
    Bt[a]          = (__bf16)hi_s[tx][n];
    Bt[a + lo_off] = (__bf16)lo_s[tx][n];
  }
}

// ===== fused prep: cnt=1 + self-loop col + al zero + split(x) + wsplit(W*) ==
__global__ __launch_bounds__(256) void prep_kernel(
    const float* __restrict__ x, __bf16* __restrict__ X2,
    const float* __restrict__ W1, __bf16* __restrict__ B1t,
    const float* __restrict__ W2, __bf16* __restrict__ B2t,
    const float* __restrict__ W3, __bf16* __restrict__ B3t,
    int* __restrict__ cnt, int* __restrict__ col,
    float* __restrict__ albase, int N){
  __shared__ float hi_s[32][33], lo_s[32][33];
  int b = blockIdx.x, t = threadIdx.x;
  int gid = b*256 + t;
  if (gid < N){
    cnt[gid] = 1;                  // self-loop pre-count
    col[gid << 7] = gid;           // self-loop entry at slot 0
  }
  // zero al_s/al_d for all 3 layers: 18N floats contiguous, float4 stores
  if (gid*4 < N*18) *(float4*)(albase + gid*4) = make_float4(0.f,0.f,0.f,0.f);

  const int nb_split = (N*32 + 255) / 256;   // 1250
  if (b < nb_split){
    int i = gid * 4;
    if (i < N*128){
      int n = i >> 7, c = i & 127;           // 4 consecutive channels, 8-aligned block
      float4 v = *(const float4*)(x + i);
      float f[4] = {v.x, v.y, v.z, v.w};
      bf16x4 h, l;
#pragma unroll
      for (int u = 0; u < 4; u++){
        __bf16 hh = (__bf16)f[u];
        h[u] = hh;
        l[u] = (__bf16)(f[u] - (float)hh);
      }
      // frame layout, K2=256: hi at k=c, lo at k=128+c (kf += 4)
      size_t a = (size_t)(n >> 4)*4096 + (size_t)(c >> 5)*512
               + (size_t)((n & 15) + 16*((c >> 3) & 3))*8 + (c & 7);
      *(bf16x4*)(X2 + a)        = h;
      *(bf16x4*)(X2 + a + 2048) = l;
    }
  } else if (b < nb_split + 64){
    int bb = b - nb_split;                   // W1: K=128 -> 4 x 16
    wsplit_body(W1, B1t, 128, 512, bb & 3, bb >> 2, hi_s, lo_s);
  } else if (b < nb_split + 64 + 256){
    int bb = b - nb_split - 64;              // W2: 16 x 16
    wsplit_body(W2, B2t, 512, 512, bb & 15, bb >> 4, hi_s, lo_s);
  } else {
    int bb = b - nb_split - 320;             // W3: 16 x 16
    wsplit_body(W3, B3t, 512, 512, bb & 15, bb >> 4, hi_s, lo_s);
  }
}

// ========== bf16 MFMA GEMM over K2=2K (hi|lo fold), f16 output ==============
// NO LDS, NO barriers (R5-verified). Operands in frame layout -> contiguous
// 1KB coalesced loads direct to VGPRs. Hb fp16 for the dot2 aggregation.
template<int H>
__global__ __launch_bounds__(256) void gemm_mfma(
    const __bf16* __restrict__ A2f, const __bf16* __restrict__ B2f,
    _Float16* __restrict__ Hb, const float* __restrict__ asrc,
    const float* __restrict__ adst, float* __restrict__ al_s,
    float* __restrict__ al_d, int M, int K2){
  int t = threadIdx.x, w = t >> 6, lane = t & 63;
  int mm = lane & 15, q = lane >> 4;

  int bid = blockIdx.x;
  int idx = bid >> 3;
  int cb = idx & 3;
  int rowblk = (bid & 7) + ((idx >> 2) << 3);   // xcd-pinned row panels
  if (rowblk * 64 >= M) return;
  int bm = rowblk * 64, bn = cb * 128;
  int wr = w & 1, wc = w >> 1;

  const int nf = K2 >> 5;                 // frames per row-block
  const int rbmax = (M >> 4) - 1;
  const __bf16* pA0; const __bf16* pA1;
  const __bf16* pB0; const __bf16* pB1; const __bf16* pB2; const __bf16* pB3;
  {
    int rb0 = (bm >> 4) + wr*2;     rb0 = (rb0 <= rbmax) ? rb0 : rbmax;
    int rb1 = (bm >> 4) + wr*2 + 1; rb1 = (rb1 <= rbmax) ? rb1 : rbmax;
    pA0 = A2f + (size_t)rb0*nf*512 + lane*8;
    pA1 = A2f + (size_t)rb1*nf*512 + lane*8;
    int rbB = (bn >> 4) + wc*4;
    pB0 = B2f + (size_t)(rbB+0)*nf*512 + lane*8;
    pB1 = B2f + (size_t)(rbB+1)*nf*512 + lane*8;
    pB2 = B2f + (size_t)(rbB+2)*nf*512 + lane*8;
    pB3 = B2f + (size_t)(rbB+3)*nf*512 + lane*8;
  }

  f32x4 acc[2][4];
#pragma unroll
  for (int i = 0; i < 2; i++)
#pragma unroll
    for (int j = 0; j < 4; j++)
#pragma unroll
      for (int r = 0; r < 4; r++) acc[i][j][r] = 0.f;

#pragma unroll 4
  for (int f = 0; f < nf; f++){
    bf16x8 a0 = *(const bf16x8*)(pA0 + (size_t)f*512);
    bf16x8 a1 = *(const bf16x8*)(pA1 + (size_t)f*512);
    bf16x8 b0 = *(const bf16x8*)(pB0 + (size_t)f*512);
    bf16x8 b1 = *(const bf16x8*)(pB1 + (size_t)f*512);
    bf16x8 b2 = *(const bf16x8*)(pB2 + (size_t)f*512);
    bf16x8 b3 = *(const bf16x8*)(pB3 + (size_t)f*512);
    acc[0][0] = __builtin_amdgcn_mfma_f32_16x16x32_bf16(a0, b0, acc[0][0], 0, 0, 0);
    acc[0][1] = __builtin_amdgcn_mfma_f32_16x16x32_bf16(a0, b1, acc[0][1], 0, 0, 0);
    acc[0][2] = __builtin_amdgcn_mfma_f32_16x16x32_bf16(a0, b2, acc[0][2], 0, 0, 0);
    acc[0][3] = __builtin_amdgcn_mfma_f32_16x16x32_bf16(a0, b3, acc[0][3], 0, 0, 0);
    acc[1][0] = __builtin_amdgcn_mfma_f32_16x16x32_bf16(a1, b0, acc[1][0], 0, 0, 0);
    acc[1][1] = __builtin_amdgcn_mfma_f32_16x16x32_bf16(a1, b1, acc[1][1], 0, 0, 0);
    acc[1][2] = __builtin_amdgcn_mfma_f32_16x16x32_bf16(a1, b2, acc[1][2], 0, 0, 0);
    acc[1][3] = __builtin_amdgcn_mfma_f32_16x16x32_bf16(a1, b3, acc[1][3], 0, 0, 0);
  }

  // ---- epilogue: Hb store (f16) + fused attention dots -----------------
  float as_v[4], ad_v[4];
#pragma unroll
  for (int j2 = 0; j2 < 4; j2++){
    int colc = bn + (wc*4 + j2)*16 + mm;
    as_v[j2] = asrc[colc];
    ad_v[j2] = adst[colc];
  }
  const int h = (H == 4) ? (bn >> 7) : 0;
#pragma unroll
  for (int i2 = 0; i2 < 2; i2++){
    int rbase = bm + (wr*2 + i2)*16 + q*4;
#pragma unroll
    for (int j2 = 0; j2 < 4; j2++){
      int colc = bn + (wc*4 + j2)*16 + mm;
#pragma unroll
      for (int r = 0; r < 4; r++){
        int row = rbase + r;
        if (row < M) Hb[(size_t)row*512 + colc] = (_Float16)acc[i2][j2][r];
      }
    }
#pragma unroll
    for (int r = 0; r < 4; r++){
      float ps = acc[i2][0][r]*as_v[0] + acc[i2][1][r]*as_v[1]
               + acc[i2][2][r]*as_v[2] + acc[i2][3][r]*as_v[3];
      float pd = acc[i2][0][r]*ad_v[0] + acc[i2][1][r]*ad_v[1]
               + acc[i2][2][r]*ad_v[2] + acc[i2][3][r]*ad_v[3];
#pragma unroll
      for (int off = 1; off < 16; off <<= 1){
        ps += __shfl_xor(ps, off);
        pd += __shfl_xor(pd, off);
      }
      int row = rbase + r;
      if (mm == 0 && row < M){
        atomicAdd(&al_s[(size_t)row*H + h], ps);
        atomicAdd(&al_d[(size_t)row*H + h], pd);
      }
    }
  }
}

// ====== channel-sliced gather, XCD-pinned, dot2 inner loop ==================
// R7: grid restored to nidx*8 x 64 thr (R5 mapping: x=g&7 -> slice s=x>>1,
// half=x&1) so XCD x only caches a 128-channel slice of Hb (2.5MB < 4MB L2;
// R6's full-row blocks thrashed L2: FETCH 48->138MB). Body keeps R6's wins:
// logits gathered ONCE into registers (2 chunks), softmax in-wave, edge-pair
// f16 dot2 inner loop. One wave per block -> no barriers (lockstep).
template<int H, int MODE>
__global__ __launch_bounds__(64) void aggregate_slice(
    const _Float16* __restrict__ Hb, const float* __restrict__ al_s,
    const float* __restrict__ al_d, const int* __restrict__ cnt,
    const int* __restrict__ col, const float* __restrict__ bias,
    float* __restrict__ outF, __bf16* __restrict__ fA,
    int nidx, int N){
  __shared__ int      src_s[64];
  __shared__ _Float16 a_sh[64];
  int g = blockIdx.x;
  int x = g & 7, idx = g >> 3;
  int s = x >> 1, half = x & 1;
  int d = half * nidx + idx;
  if (d >= N) return;
  int lane = threadIdx.x;
  const int hh = (H == 1) ? 0 : s;
  const float ald = al_d[(size_t)d*H + hh];
  int deg = cnt[d]; deg = (deg < CAP) ? deg : CAP;
  int start = d << 7;

  // gather logits once (<= 2 chunks), keep in registers
  int sc0 = 0, sc1 = 0;
  float v0f = -1e30f, v1f = -1e30f;
  if (lane < deg){
    sc0 = col[start + lane];
    float v = al_s[(size_t)sc0*H + hh] + ald;
    v0f = (v > 0.f) ? v : NSLOPE * v;
  }
  if (64 + lane < deg){
    sc1 = col[start + 64 + lane];
    float v = al_s[(size_t)sc1*H + hh] + ald;
    v1f = (v > 0.f) ? v : NSLOPE * v;
  }
  float mx = fmaxf(v0f, v1f);
#pragma unroll
  for (int off = 32; off > 0; off >>= 1)
    mx = fmaxf(mx, __shfl_xor(mx, off));

  float e0 = (lane < deg)      ? __expf(v0f - mx) : 0.f;
  float e1 = (64 + lane < deg) ? __expf(v1f - mx) : 0.f;
  float lsum = e0 + e1;
#pragma unroll
  for (int off = 32; off > 0; off >>= 1)
    lsum += __shfl_xor(lsum, off);

  const unsigned* __restrict__ Hb32 = (const unsigned*)Hb;   // row = 256 u32
  const unsigned coffu = s*64 + lane;                        // channel pair idx
  float accx = 0.f, accy = 0.f;

  int cc0 = (deg < 64) ? deg : 64;       // chunk A count
  src_s[lane] = sc0;
  a_sh[lane]  = (_Float16)e0;
  for (int chunk = 0; ; chunk++){
    int cnt2 = (chunk == 0) ? cc0 : (deg - 64);
    int npair = cnt2 >> 1;
    int j = 0;
    for (; j + 2 <= npair; j += 2){
      int s0 = src_s[2*j],     s1 = src_s[2*j+1];
      int s2 = src_s[2*j+2],   s3 = src_s[2*j+3];
      unsigned a01 = *(const unsigned*)&a_sh[2*j];
      unsigned a23 = *(const unsigned*)&a_sh[2*j+2];
      unsigned u0 = Hb32[(size_t)s0*256 + coffu];
      unsigned u1 = Hb32[(size_t)s1*256 + coffu];
      unsigned u2 = Hb32[(size_t)s2*256 + coffu];
      unsigned u3 = Hb32[(size_t)s3*256 + coffu];
      unsigned pc  = (u0 & 0x0000ffffu) | (u1 << 16);   // (e0_c , e1_c )
      unsigned pc1 = (u0 >> 16) | (u1 & 0xffff0000u);   // (e0_c1, e1_c1)
      unsigned qc  = (u2 & 0x0000ffffu) | (u3 << 16);
      unsigned qc1 = (u2 >> 16) | (u3 & 0xffff0000u);
      accx = dot2f(pc,  a01, accx);
      accy = dot2f(pc1, a01, accy);
      accx = dot2f(qc,  a23, accx);
      accy = dot2f(qc1, a23, accy);
    }
    for (; j < npair; j++){
      int s0 = src_s[2*j], s1 = src_s[2*j+1];
      unsigned a01 = *(const unsigned*)&a_sh[2*j];
      unsigned u0 = Hb32[(size_t)s0*256 + coffu];
      unsigned u1 = Hb32[(size_t)s1*256 + coffu];
      unsigned pc  = (u0 & 0x0000ffffu) | (u1 << 16);
      unsigned pc1 = (u0 >> 16) | (u1 & 0xffff0000u);
      accx = dot2f(pc,  a01, accx);
      accy = dot2f(pc1, a01, accy);
    }
    if (cnt2 & 1){
      int sl = src_s[cnt2 - 1];
      float al = (float)a_sh[cnt2 - 1];
      unsigned ul = Hb32[(size_t)sl*256 + coffu];
      half2v hv = __builtin_bit_cast(half2v, ul);
      accx += al * (float)hv[0];
      accy += al * (float)hv[1];
    }
    if (chunk == 1 || deg <= 64) break;
    // lockstep wave, in-order DS ops: chunk-A reads precede this overwrite
    src_s[lane] = sc1;
    a_sh[lane]  = (_Float16)e1;
  }

  float invd = 1.f / lsum;
  int c = s*128 + lane*2;
  float2 bv = *(const float2*)(bias + c);
  float r0 = accx * invd + bv.x;
  float r1 = accy * invd + bv.y;
  if (MODE == 1){
    r0 = fmaxf(r0, 0.f); r1 = fmaxf(r1, 0.f);
    __bf16 h0 = (__bf16)r0, h1 = (__bf16)r1;
    bf16x2 hv; hv[0] = h0; hv[1] = h1;
    bf16x2 lv; lv[0] = (__bf16)(r0 - (float)h0); lv[1] = (__bf16)(r1 - (float)h1);
    // frame layout write (K2=1024): hi at k=c, lo at k=512+c
    size_t a = (size_t)(d >> 4)*16384 + (size_t)(c >> 5)*512
             + (size_t)((d & 15) + 16*((c >> 3) & 3))*8 + (c & 7);
    *(bf16x2*)(fA + a)        = hv;
    *(bf16x2*)(fA + a + 8192) = lv;
  } else {
    *(float2*)(outF + (size_t)d*512 + c) = make_float2(r0, r1);
  }
}

// =========================== launch =========================================
extern "C" void kernel_launch(void* const* d_in, const int* in_sizes, int n_in,
                              void* d_out, int out_size, void* d_ws, size_t ws_size,
                              hipStream_t stream){
  const float* x   = (const float*)d_in[0];
  const int*   ei  = (const int*)  d_in[1];
  const float* W1  = (const float*)d_in[2];
  const float* as1 = (const float*)d_in[3];
  const float* ad1 = (const float*)d_in[4];
  const float* b1  = (const float*)d_in[5];
  const float* W2  = (const float*)d_in[6];
  const float* as2 = (const float*)d_in[7];
  const float* ad2 = (const float*)d_in[8];
  const float* b2  = (const float*)d_in[9];
  const float* W3  = (const float*)d_in[10];
  const float* as3 = (const float*)d_in[11];
  const float* ad3 = (const float*)d_in[12];
  const float* b3  = (const float*)d_in[13];
  float* out = (float*)d_out;

  const int N = in_sizes[0] / 128;   // 10000
  const int E = in_sizes[1] / 2;     // 320000
  const int nidx = (N + 1) / 2;

  // workspace carve-up
  __bf16* feat2  = (__bf16*)d_ws;                     // N*1024 bf16 (frame, hi|lo)
  __bf16* X2     = feat2 + (size_t)N*1024;            // N*256 bf16 (frame, layer-1 A)
  float*  albase = (float*)(X2 + (size_t)N*256);      // 18*N floats total:
  float*  als1   = albase;                            //  N*4
  float*  ald1   = als1 + (size_t)N*4;                //  N*4
  float*  als2   = ald1 + (size_t)N*4;                //  N*4
  float*  ald2   = als2 + (size_t)N*4;                //  N*4
  float*  als3   = ald2 + (size_t)N*4;                //  N
  float*  ald3   = als3 + (size_t)N;                  //  N
  int*    cnt    = (int*)(ald3 + (size_t)N);          // N
  int*    col    = cnt + N;                           // N*CAP
  uintptr_t p  = (uintptr_t)(col + (size_t)N*CAP);
  p = (p + 15) & ~(uintptr_t)15;
  __bf16* B1t = (__bf16*)p;                           // 512*256 bf16 (frame)
  __bf16* B2t = B1t + 512*256;                        // 512*1024 bf16 (frame)
  __bf16* B3t = B2t + 512*1024;                       // 512*1024 bf16 (frame)
  _Float16* Hb = (_Float16*)(B3t + 512*1024);         // N*512 f16 (row-major, gather)

  const int nb_split = (N*32 + 255)/256;              // 1250
  const int pgrid = nb_split + 64 + 256 + 256;        // 1826

  // prep: cnt=1 + self-loop col + al-zero, split x, split W1/W2/W3
  prep_kernel<<<pgrid, 256, 0, stream>>>(x, X2, W1, B1t, W2, B2t, W3, B3t,
                                         cnt, col, albase, N);
  fill_kernel<<<(E+255)/256, 256, 0, stream>>>(ei, E, cnt, col);

  const int nrb = (N + 63)/64;                        // 157 row panels (BM=64)
  const int ggrid = (((nrb + 7) >> 3) << 3) * 4;      // 160*4 = 640 (XCD map)
  const int agrid = nidx * 8;

  // ---- layer 1: x[N,128] @ W1[128,512]  (K2 = 256) ----
  gemm_mfma<4><<<ggrid, 256, 0, stream>>>(X2, B1t, Hb, as1, ad1, als1, ald1, N, 256);
  aggregate_slice<4,1><<<agrid, 64, 0, stream>>>(Hb, als1, ald1, cnt, col, b1,
      (float*)nullptr, feat2, nidx, N);

  // ---- layer 2: feat[N,512] @ W2[512,512]  (K2 = 1024) ----
  gemm_mfma<4><<<ggrid, 256, 0, stream>>>(feat2, B2t, Hb, as2, ad2, als2, ald2, N, 1024);
  aggregate_slice<4,1><<<agrid, 64, 0, stream>>>(Hb, als2, ald2, cnt, col, b2,
      (float*)nullptr, feat2, nidx, N);

  // ---- layer 3: feat[N,512] @ W3[512,512], heads=1  (K2 = 1024) ----
  gemm_mfma<1><<<ggrid, 256, 0, stream>>>(feat2, B3t, Hb, as3, ad3, als3, ald3, N, 1024);
  aggregate_slice<1,0><<<agrid, 64, 0, stream>>>(Hb, als3, ald3, cnt, col, b3,
      out, (__bf16*)nullptr, nidx, N);
}

// Round 9
// 266.944 us; speedup vs baseline: 1.2560x; 1.0806x over previous
//
#include <hip/hip_runtime.h>

#define NSLOPE 0.2f
#define CAP 128            // bucket capacity per dst node (max degree ~66 incl. self-loop)

typedef __bf16 bf16x8 __attribute__((ext_vector_type(8)));
typedef __bf16 bf16x4 __attribute__((ext_vector_type(4)));
typedef __bf16 bf16x2 __attribute__((ext_vector_type(2)));
typedef float  f32x4  __attribute__((ext_vector_type(4)));
typedef _Float16 half2v __attribute__((ext_vector_type(2)));

// fp16 pair dot with f32 accumulate: one v_dot2_f32_f16 when available.
static __device__ __forceinline__ float dot2f(unsigned p, unsigned a, float c){
#if __has_builtin(__builtin_amdgcn_fdot2)
  return __builtin_amdgcn_fdot2(__builtin_bit_cast(half2v, p),
                                __builtin_bit_cast(half2v, a), c, false);
#else
  half2v ph = __builtin_bit_cast(half2v, p), ah = __builtin_bit_cast(half2v, a);
  return c + (float)ph[0]*(float)ah[0] + (float)ph[1]*(float)ah[1];
#endif
}

// ============================================================================
// FRAME LAYOUT: matrix [R rows][K cols] bf16 stored as frames of 16 rows x
// 32 k. Frame (rb, kf) holds lane slot = (row&15) + 16*((k>>3)&3), elem k&7.
// Element addr (bf16 units) = rb*(K*16) + kf*512 + slot*8 + (k&7).
// A GEMM fragment load is then ptr + f*512 + lane*8 : contiguous 1KB/instr.
// R8: hi|lo fold DROPPED. The old fold paired A_lo with B_lo (frame f of A
// against frame f of B), so cross terms were never computed -> it contributed
// only the ~1e-7 lo*lo terms. Plain bf16 gives the same absmax at half the
// GEMM cost. K = 128 (layer 1) / 512 (layers 2,3).
// ============================================================================

// ===== bucket fill: append edges after prep pre-inserted self-loops =========
__global__ void fill_kernel(const int* __restrict__ ei, int E,
                            int* cnt, int* __restrict__ col){
  int i = blockIdx.x*blockDim.x + threadIdx.x;
  if (i < E){
    int s = ei[i], d = ei[E + i];
    int slot = atomicAdd(&cnt[d], 1);
    if (slot < CAP) col[(d << 7) + slot] = s;   // CAP==128
  }
}

// ===== W [K][Nc] fp32 -> frame-layout bf16 B ================================
__device__ __forceinline__ void wsplit_body(
    const float* __restrict__ W, __bf16* __restrict__ Bt, int K, int Nc,
    int kb, int nb, float (*hi_s)[33]){
  int tx = threadIdx.x & 31, ty = threadIdx.x >> 5;   // 32 x 8
  int k0 = kb * 32, n0 = nb * 32;
#pragma unroll
  for (int i = 0; i < 4; i++){
    int r = ty + i*8;
    hi_s[r][tx] = (float)(__bf16)W[(size_t)(k0 + r)*Nc + n0 + tx];
  }
  __syncthreads();
  const size_t Kx16 = (size_t)K * 16;          // 16-row block stride
#pragma unroll
  for (int i = 0; i < 4; i++){
    int n = ty + i*8;
    int r = n0 + n;                            // B row = W col
    size_t a = (size_t)(r >> 4)*Kx16 + (size_t)(k0 >> 5)*512
             + (size_t)((r & 15) + 16*(tx >> 3))*8 + (tx & 7);
    Bt[a] = (__bf16)hi_s[tx][n];
  }
}

// ===== fused prep: cnt=1 + self-loop col + al zero + pack(x) + pack(W*) =====
__global__ __launch_bounds__(256) void prep_kernel(
    const float* __restrict__ x, __bf16* __restrict__ X2,
    const float* __restrict__ W1, __bf16* __restrict__ B1t,
    const float* __restrict__ W2, __bf16* __restrict__ B2t,
    const float* __restrict__ W3, __bf16* __restrict__ B3t,
    int* __restrict__ cnt, int* __restrict__ col,
    float* __restrict__ albase, int N){
  __shared__ float hi_s[32][33];
  int b = blockIdx.x, t = threadIdx.x;
  int gid = b*256 + t;
  if (gid < N){
    cnt[gid] = 1;                  // self-loop pre-count
    col[gid << 7] = gid;           // self-loop entry at slot 0
  }
  // zero al_s/al_d for all 3 layers: 18N floats contiguous, float4 stores
  if (gid*4 < N*18) *(float4*)(albase + gid*4) = make_float4(0.f,0.f,0.f,0.f);

  const int nb_split = (N*32 + 255) / 256;   // 1250
  if (b < nb_split){
    int i = gid * 4;
    if (i < N*128){
      int n = i >> 7, c = i & 127;           // 4 consecutive channels
      float4 v = *(const float4*)(x + i);
      float f[4] = {v.x, v.y, v.z, v.w};
      bf16x4 h;
#pragma unroll
      for (int u = 0; u < 4; u++) h[u] = (__bf16)f[u];
      // frame layout, K=128
      size_t a = (size_t)(n >> 4)*2048 + (size_t)(c >> 5)*512
               + (size_t)((n & 15) + 16*((c >> 3) & 3))*8 + (c & 7);
      *(bf16x4*)(X2 + a) = h;
    }
  } else if (b < nb_split + 64){
    int bb = b - nb_split;                   // W1: K=128 -> 4 x 16
    wsplit_body(W1, B1t, 128, 512, bb & 3, bb >> 2, hi_s);
  } else if (b < nb_split + 64 + 256){
    int bb = b - nb_split - 64;              // W2: 16 x 16
    wsplit_body(W2, B2t, 512, 512, bb & 15, bb >> 4, hi_s);
  } else {
    int bb = b - nb_split - 320;             // W3: 16 x 16
    wsplit_body(W3, B3t, 512, 512, bb & 15, bb >> 4, hi_s);
  }
}

// ========== bf16 MFMA GEMM, f16 output ======================================
// NO LDS, NO barriers (R5-verified). Operands in frame layout -> contiguous
// 1KB coalesced loads direct to VGPRs. K halved in R8 (no hi|lo fold).
template<int H>
__global__ __launch_bounds__(256) void gemm_mfma(
    const __bf16* __restrict__ A2f, const __bf16* __restrict__ B2f,
    _Float16* __restrict__ Hb, const float* __restrict__ asrc,
    const float* __restrict__ adst, float* __restrict__ al_s,
    float* __restrict__ al_d, int M, int K2){
  int t = threadIdx.x, w = t >> 6, lane = t & 63;
  int mm = lane & 15, q = lane >> 4;

  int bid = blockIdx.x;
  int idx = bid >> 3;
  int cb = idx & 3;
  int rowblk = (bid & 7) + ((idx >> 2) << 3);   // xcd-pinned row panels
  if (rowblk * 64 >= M) return;
  int bm = rowblk * 64, bn = cb * 128;
  int wr = w & 1, wc = w >> 1;

  const int nf = K2 >> 5;                 // frames per row-block
  const int rbmax = (M >> 4) - 1;
  const __bf16* pA0; const __bf16* pA1;
  const __bf16* pB0; const __bf16* pB1; const __bf16* pB2; const __bf16* pB3;
  {
    int rb0 = (bm >> 4) + wr*2;     rb0 = (rb0 <= rbmax) ? rb0 : rbmax;
    int rb1 = (bm >> 4) + wr*2 + 1; rb1 = (rb1 <= rbmax) ? rb1 : rbmax;
    pA0 = A2f + (size_t)rb0*nf*512 + lane*8;
    pA1 = A2f + (size_t)rb1*nf*512 + lane*8;
    int rbB = (bn >> 4) + wc*4;
    pB0 = B2f + (size_t)(rbB+0)*nf*512 + lane*8;
    pB1 = B2f + (size_t)(rbB+1)*nf*512 + lane*8;
    pB2 = B2f + (size_t)(rbB+2)*nf*512 + lane*8;
    pB3 = B2f + (size_t)(rbB+3)*nf*512 + lane*8;
  }

  f32x4 acc[2][4];
#pragma unroll
  for (int i = 0; i < 2; i++)
#pragma unroll
    for (int j = 0; j < 4; j++)
#pragma unroll
      for (int r = 0; r < 4; r++) acc[i][j][r] = 0.f;

#pragma unroll 4
  for (int f = 0; f < nf; f++){
    bf16x8 a0 = *(const bf16x8*)(pA0 + (size_t)f*512);
    bf16x8 a1 = *(const bf16x8*)(pA1 + (size_t)f*512);
    bf16x8 b0 = *(const bf16x8*)(pB0 + (size_t)f*512);
    bf16x8 b1 = *(const bf16x8*)(pB1 + (size_t)f*512);
    bf16x8 b2 = *(const bf16x8*)(pB2 + (size_t)f*512);
    bf16x8 b3 = *(const bf16x8*)(pB3 + (size_t)f*512);
    acc[0][0] = __builtin_amdgcn_mfma_f32_16x16x32_bf16(a0, b0, acc[0][0], 0, 0, 0);
    acc[0][1] = __builtin_amdgcn_mfma_f32_16x16x32_bf16(a0, b1, acc[0][1], 0, 0, 0);
    acc[0][2] = __builtin_amdgcn_mfma_f32_16x16x32_bf16(a0, b2, acc[0][2], 0, 0, 0);
    acc[0][3] = __builtin_amdgcn_mfma_f32_16x16x32_bf16(a0, b3, acc[0][3], 0, 0, 0);
    acc[1][0] = __builtin_amdgcn_mfma_f32_16x16x32_bf16(a1, b0, acc[1][0], 0, 0, 0);
    acc[1][1] = __builtin_amdgcn_mfma_f32_16x16x32_bf16(a1, b1, acc[1][1], 0, 0, 0);
    acc[1][2] = __builtin_amdgcn_mfma_f32_16x16x32_bf16(a1, b2, acc[1][2], 0, 0, 0);
    acc[1][3] = __builtin_amdgcn_mfma_f32_16x16x32_bf16(a1, b3, acc[1][3], 0, 0, 0);
  }

  // ---- epilogue: Hb store (f16) + fused attention dots -----------------
  float as_v[4], ad_v[4];
#pragma unroll
  for (int j2 = 0; j2 < 4; j2++){
    int colc = bn + (wc*4 + j2)*16 + mm;
    as_v[j2] = asrc[colc];
    ad_v[j2] = adst[colc];
  }
  const int h = (H == 4) ? (bn >> 7) : 0;
#pragma unroll
  for (int i2 = 0; i2 < 2; i2++){
    int rbase = bm + (wr*2 + i2)*16 + q*4;
#pragma unroll
    for (int j2 = 0; j2 < 4; j2++){
      int colc = bn + (wc*4 + j2)*16 + mm;
#pragma unroll
      for (int r = 0; r < 4; r++){
        int row = rbase + r;
        if (row < M) Hb[(size_t)row*512 + colc] = (_Float16)acc[i2][j2][r];
      }
    }
#pragma unroll
    for (int r = 0; r < 4; r++){
      float ps = acc[i2][0][r]*as_v[0] + acc[i2][1][r]*as_v[1]
               + acc[i2][2][r]*as_v[2] + acc[i2][3][r]*as_v[3];
      float pd = acc[i2][0][r]*ad_v[0] + acc[i2][1][r]*ad_v[1]
               + acc[i2][2][r]*ad_v[2] + acc[i2][3][r]*ad_v[3];
#pragma unroll
      for (int off = 1; off < 16; off <<= 1){
        ps += __shfl_xor(ps, off);
        pd += __shfl_xor(pd, off);
      }
      int row = rbase + r;
      if (mm == 0 && row < M){
        atomicAdd(&al_s[(size_t)row*H + h], ps);
        atomicAdd(&al_d[(size_t)row*H + h], pd);
      }
    }
  }
}

// ====== channel-sliced gather, XCD-pinned, dot2 inner loop (R7-verified) ====
template<int H, int MODE>
__global__ __launch_bounds__(64) void aggregate_slice(
    const _Float16* __restrict__ Hb, const float* __restrict__ al_s,
    const float* __restrict__ al_d, const int* __restrict__ cnt,
    const int* __restrict__ col, const float* __restrict__ bias,
    float* __restrict__ outF, __bf16* __restrict__ fA,
    int nidx, int N){
  __shared__ int      src_s[64];
  __shared__ _Float16 a_sh[64];
  int g = blockIdx.x;
  int x = g & 7, idx = g >> 3;
  int s = x >> 1, half = x & 1;
  int d = half * nidx + idx;
  if (d >= N) return;
  int lane = threadIdx.x;
  const int hh = (H == 1) ? 0 : s;
  const float ald = al_d[(size_t)d*H + hh];
  int deg = cnt[d]; deg = (deg < CAP) ? deg : CAP;
  int start = d << 7;

  // gather logits once (<= 2 chunks), keep in registers
  int sc0 = 0, sc1 = 0;
  float v0f = -1e30f, v1f = -1e30f;
  if (lane < deg){
    sc0 = col[start + lane];
    float v = al_s[(size_t)sc0*H + hh] + ald;
    v0f = (v > 0.f) ? v : NSLOPE * v;
  }
  if (64 + lane < deg){
    sc1 = col[start + 64 + lane];
    float v = al_s[(size_t)sc1*H + hh] + ald;
    v1f = (v > 0.f) ? v : NSLOPE * v;
  }
  float mx = fmaxf(v0f, v1f);
#pragma unroll
  for (int off = 32; off > 0; off >>= 1)
    mx = fmaxf(mx, __shfl_xor(mx, off));

  float e0 = (lane < deg)      ? __expf(v0f - mx) : 0.f;
  float e1 = (64 + lane < deg) ? __expf(v1f - mx) : 0.f;
  float lsum = e0 + e1;
#pragma unroll
  for (int off = 32; off > 0; off >>= 1)
    lsum += __shfl_xor(lsum, off);

  const unsigned* __restrict__ Hb32 = (const unsigned*)Hb;   // row = 256 u32
  const unsigned coffu = s*64 + lane;                        // channel pair idx
  float accx = 0.f, accy = 0.f;

  int cc0 = (deg < 64) ? deg : 64;       // chunk A count
  src_s[lane] = sc0;
  a_sh[lane]  = (_Float16)e0;
  for (int chunk = 0; ; chunk++){
    int cnt2 = (chunk == 0) ? cc0 : (deg - 64);
    int npair = cnt2 >> 1;
    int j = 0;
    for (; j + 2 <= npair; j += 2){
      int s0 = src_s[2*j],     s1 = src_s[2*j+1];
      int s2 = src_s[2*j+2],   s3 = src_s[2*j+3];
      unsigned a01 = *(const unsigned*)&a_sh[2*j];
      unsigned a23 = *(const unsigned*)&a_sh[2*j+2];
      unsigned u0 = Hb32[(size_t)s0*256 + coffu];
      unsigned u1 = Hb32[(size_t)s1*256 + coffu];
      unsigned u2 = Hb32[(size_t)s2*256 + coffu];
      unsigned u3 = Hb32[(size_t)s3*256 + coffu];
      unsigned pc  = (u0 & 0x0000ffffu) | (u1 << 16);   // (e0_c , e1_c )
      unsigned pc1 = (u0 >> 16) | (u1 & 0xffff0000u);   // (e0_c1, e1_c1)
      unsigned qc  = (u2 & 0x0000ffffu) | (u3 << 16);
      unsigned qc1 = (u2 >> 16) | (u3 & 0xffff0000u);
      accx = dot2f(pc,  a01, accx);
      accy = dot2f(pc1, a01, accy);
      accx = dot2f(qc,  a23, accx);
      accy = dot2f(qc1, a23, accy);
    }
    for (; j < npair; j++){
      int s0 = src_s[2*j], s1 = src_s[2*j+1];
      unsigned a01 = *(const unsigned*)&a_sh[2*j];
      unsigned u0 = Hb32[(size_t)s0*256 + coffu];
      unsigned u1 = Hb32[(size_t)s1*256 + coffu];
      unsigned pc  = (u0 & 0x0000ffffu) | (u1 << 16);
      unsigned pc1 = (u0 >> 16) | (u1 & 0xffff0000u);
      accx = dot2f(pc,  a01, accx);
      accy = dot2f(pc1, a01, accy);
    }
    if (cnt2 & 1){
      int sl = src_s[cnt2 - 1];
      float al = (float)a_sh[cnt2 - 1];
      unsigned ul = Hb32[(size_t)sl*256 + coffu];
      half2v hv = __builtin_bit_cast(half2v, ul);
      accx += al * (float)hv[0];
      accy += al * (float)hv[1];
    }
    if (chunk == 1 || deg <= 64) break;
    // lockstep wave, in-order DS ops: chunk-A reads precede this overwrite
    src_s[lane] = sc1;
    a_sh[lane]  = (_Float16)e1;
  }

  float invd = 1.f / lsum;
  int c = s*128 + lane*2;
  float2 bv = *(const float2*)(bias + c);
  float r0 = accx * invd + bv.x;
  float r1 = accy * invd + bv.y;
  if (MODE == 1){
    r0 = fmaxf(r0, 0.f); r1 = fmaxf(r1, 0.f);
    bf16x2 hv; hv[0] = (__bf16)r0; hv[1] = (__bf16)r1;
    // frame layout write (K=512): rb stride 512*16 = 8192
    size_t a = (size_t)(d >> 4)*8192 + (size_t)(c >> 5)*512
             + (size_t)((d & 15) + 16*((c >> 3) & 3))*8 + (c & 7);
    *(bf16x2*)(fA + a) = hv;
  } else {
    *(float2*)(outF + (size_t)d*512 + c) = make_float2(r0, r1);
  }
}

// =========================== launch =========================================
extern "C" void kernel_launch(void* const* d_in, const int* in_sizes, int n_in,
                              void* d_out, int out_size, void* d_ws, size_t ws_size,
                              hipStream_t stream){
  const float* x   = (const float*)d_in[0];
  const int*   ei  = (const int*)  d_in[1];
  const float* W1  = (const float*)d_in[2];
  const float* as1 = (const float*)d_in[3];
  const float* ad1 = (const float*)d_in[4];
  const float* b1  = (const float*)d_in[5];
  const float* W2  = (const float*)d_in[6];
  const float* as2 = (const float*)d_in[7];
  const float* ad2 = (const float*)d_in[8];
  const float* b2  = (const float*)d_in[9];
  const float* W3  = (const float*)d_in[10];
  const float* as3 = (const float*)d_in[11];
  const float* ad3 = (const float*)d_in[12];
  const float* b3  = (const float*)d_in[13];
  float* out = (float*)d_out;

  const int N = in_sizes[0] / 128;   // 10000
  const int E = in_sizes[1] / 2;     // 320000
  const int nidx = (N + 1) / 2;

  // workspace carve-up
  __bf16* feat2  = (__bf16*)d_ws;                     // N*512 bf16 (frame)
  __bf16* X2     = feat2 + (size_t)N*512;             // N*128 bf16 (frame, layer-1 A)
  float*  albase = (float*)(X2 + (size_t)N*128);      // 18*N floats total:
  float*  als1   = albase;                            //  N*4
  float*  ald1   = als1 + (size_t)N*4;                //  N*4
  float*  als2   = ald1 + (size_t)N*4;                //  N*4
  float*  ald2   = als2 + (size_t)N*4;                //  N*4
  float*  als3   = ald2 + (size_t)N*4;                //  N
  float*  ald3   = als3 + (size_t)N;                  //  N
  int*    cnt    = (int*)(ald3 + (size_t)N);          // N
  int*    col    = cnt + N;                           // N*CAP
  uintptr_t p  = (uintptr_t)(col + (size_t)N*CAP);
  p = (p + 15) & ~(uintptr_t)15;
  __bf16* B1t = (__bf16*)p;                           // 512*128 bf16 (frame)
  __bf16* B2t = B1t + 512*128;                        // 512*512 bf16 (frame)
  __bf16* B3t = B2t + 512*512;                        // 512*512 bf16 (frame)
  _Float16* Hb = (_Float16*)(B3t + 512*512);          // N*512 f16 (row-major, gather)

  const int nb_split = (N*32 + 255)/256;              // 1250
  const int pgrid = nb_split + 64 + 256 + 256;        // 1826

  // prep: cnt=1 + self-loop col + al-zero, pack x, pack W1/W2/W3
  prep_kernel<<<pgrid, 256, 0, stream>>>(x, X2, W1, B1t, W2, B2t, W3, B3t,
                                         cnt, col, albase, N);
  fill_kernel<<<(E+255)/256, 256, 0, stream>>>(ei, E, cnt, col);

  const int nrb = (N + 63)/64;                        // 157 row panels (BM=64)
  const int ggrid = (((nrb + 7) >> 3) << 3) * 4;      // 160*4 = 640 (XCD map)
  const int agrid = nidx * 8;

  // ---- layer 1: x[N,128] @ W1[128,512]  (K = 128) ----
  gemm_mfma<4><<<ggrid, 256, 0, stream>>>(X2, B1t, Hb, as1, ad1, als1, ald1, N, 128);
  aggregate_slice<4,1><<<agrid, 64, 0, stream>>>(Hb, als1, ald1, cnt, col, b1,
      (float*)nullptr, feat2, nidx, N);

  // ---- layer 2: feat[N,512] @ W2[512,512]  (K = 512) ----
  gemm_mfma<4><<<ggrid, 256, 0, stream>>>(feat2, B2t, Hb, as2, ad2, als2, ald2, N, 512);
  aggregate_slice<4,1><<<agrid, 64, 0, stream>>>(Hb, als2, ald2, cnt, col, b2,
      (float*)nullptr, feat2, nidx, N);

  // ---- layer 3: feat[N,512] @ W3[512,512], heads=1  (K = 512) ----
  gemm_mfma<1><<<ggrid, 256, 0, stream>>>(feat2, B3t, Hb, as3, ad3, als3, ald3, N, 512);
  aggregate_slice<1,0><<<agrid, 64, 0, stream>>>(Hb, als3, ald3, cnt, col, b3,
      out, (__bf16*)nullptr, nidx, N);
}